// Round 1
// baseline (1799.014 us; speedup 1.0000x reference)
//
#include <hip/hip_runtime.h>

#define NB 112
#define SEQ 128
#define DM 768
#define NH 12
#define HD 64
#define FF 3072
#define NLAYER 3
#define MTOK (NB*SEQ)            // 14336
#define QKVN (3*DM)              // 2304
#define HEADTOT (NB*NH)          // 1344
#define QSZ ((size_t)HEADTOT*SEQ*HD)   // 11010048 elems per q/k/v
#define BNBLK 448                 // 14336/32 rows

typedef unsigned short u16;
typedef __attribute__((ext_vector_type(8))) short short8;
typedef __attribute__((ext_vector_type(4))) float f32x4;
typedef __attribute__((ext_vector_type(4))) unsigned short us4;

__device__ __forceinline__ u16 f2bf(float f){
  unsigned u = __builtin_bit_cast(unsigned, f);
  u += 0x7FFFu + ((u >> 16) & 1u);
  return (u16)(u >> 16);
}

__device__ __forceinline__ void gl_lds16(const void* g, void* l){
  __builtin_amdgcn_global_load_lds((const __attribute__((address_space(1))) unsigned*)g,
                                   (__attribute__((address_space(3))) unsigned*)l, 16, 0, 0);
}

// ---------------- GEMM: C[m,n] = sum_k A[m,k] * W[n,k]  (A,W bf16; acc f32) ----
// EPI: 1 = gelu(acc+bias) -> bf16 row-major    (FFN1)
//      2 = acc+bias+res   -> f32 row-major     (O-proj, FFN2)
//      3 = acc+bias       -> bf16 qkv head-scatter [which][b][h][l][e]  (QKV)
#define BM 128
#define BN 128
#define BK 32

template<int EPI>
__global__ __launch_bounds__(256)
void gemm_bt(const u16* __restrict__ A, const u16* __restrict__ W,
             const float* __restrict__ bias, u16* __restrict__ obf,
             float* __restrict__ of32, const float* __restrict__ res,
             int M, int N, int K)
{
  __shared__ __align__(16) u16 As[BM*BK];
  __shared__ __align__(16) u16 Bs[BN*BK];
  const int tid = threadIdx.x;
  const int w = tid >> 6, lane = tid & 63;
  const int bm = blockIdx.y * BM, bn = blockIdx.x * BN;
  const int wm = (w >> 1) * 64, wn = (w & 1) * 64;
  const int srow = w * 32 + (lane >> 2);
  const int scol = (lane & 3) * 8;
  const u16* Ag = A + (size_t)(bm + srow) * K + scol;
  const u16* Bg = W + (size_t)(bn + srow) * K + scol;
  u16* Asl0 = &As[(w * 32) * BK];
  u16* Asl1 = &As[(w * 32 + 16) * BK];
  u16* Bsl0 = &Bs[(w * 32) * BK];
  u16* Bsl1 = &Bs[(w * 32 + 16) * BK];
  const size_t row16 = (size_t)16 * K;
  const int fr = lane & 15, fko = (lane >> 4) * 8;
  f32x4 acc[4][4] = {};
  for (int kt = 0; kt < K; kt += BK) {
    __syncthreads();
    gl_lds16(Ag + kt, Asl0);
    gl_lds16(Ag + kt + row16, Asl1);
    gl_lds16(Bg + kt, Bsl0);
    gl_lds16(Bg + kt + row16, Bsl1);
    __syncthreads();
    short8 af[4], bf[4];
    #pragma unroll
    for (int i = 0; i < 4; i++) af[i] = *(const short8*)&As[(wm + i*16 + fr)*BK + fko];
    #pragma unroll
    for (int i = 0; i < 4; i++) bf[i] = *(const short8*)&Bs[(wn + i*16 + fr)*BK + fko];
    #pragma unroll
    for (int mi = 0; mi < 4; mi++)
      #pragma unroll
      for (int ni = 0; ni < 4; ni++)
        acc[mi][ni] = __builtin_amdgcn_mfma_f32_16x16x32_bf16(af[mi], bf[ni], acc[mi][ni], 0, 0, 0);
  }
  const int fg = lane >> 4;
  #pragma unroll
  for (int mi = 0; mi < 4; mi++) {
    #pragma unroll
    for (int ni = 0; ni < 4; ni++) {
      const int c = bn + wn + ni*16 + fr;
      const int r0 = bm + wm + mi*16 + fg*4;
      const float bc = bias[c];
      #pragma unroll
      for (int j = 0; j < 4; j++) {
        float v = acc[mi][ni][j] + bc;
        const int r = r0 + j;
        if constexpr (EPI == 1) {
          v = 0.5f * v * (1.0f + erff(v * 0.70710678118654752f));
          obf[(size_t)r * N + c] = f2bf(v);
        } else if constexpr (EPI == 2) {
          of32[(size_t)r * N + c] = v + res[(size_t)r * N + c];
        } else {
          const int which = c / DM;
          const int cc = c - which * DM;
          const int hh = cc >> 6, e = cc & 63;
          const int bb = r >> 7, l = r & 127;
          obf[(size_t)which * QSZ + ((size_t)(bb*NH + hh) * SEQ + l) * HD + e] = f2bf(v);
        }
      }
    }
  }
}

// ---------------- Attention: one block per (b,h) -----------------------------
__global__ __launch_bounds__(256)
void attn_kernel(const u16* __restrict__ qkvb, const float* __restrict__ biasT,
                 u16* __restrict__ ab)
{
  const int h = blockIdx.x, b = blockIdx.y;
  const int tid = threadIdx.x, w = tid >> 6, lane = tid & 63;
  const int bh = b * NH + h;
  const u16* qp = qkvb + (size_t)bh * SEQ * HD;
  const u16* kp = qkvb + QSZ + (size_t)bh * SEQ * HD;
  const u16* vp = qkvb + 2 * QSZ + (size_t)bh * SEQ * HD;
  __shared__ __align__(16) u16 vT[HD * 136];   // v transposed [e][s], pad 8
  __shared__ __align__(16) u16 P[SEQ * 136];   // softmax probs bf16
  // stage V transposed
  {
    const int s = tid & 127, half = tid >> 7;
    #pragma unroll
    for (int rr = 0; rr < 4; rr++) {
      const int e0 = half * 32 + rr * 8;
      short8 v8 = *(const short8*)&vp[s * HD + e0];
      #pragma unroll
      for (int j = 0; j < 8; j++) vT[(e0 + j) * 136 + s] = (u16)v8[j];
    }
  }
  const int fr = lane & 15, fg = lane >> 4;
  // S = q k^T  (wave w owns rows [w*32, w*32+32))
  f32x4 sacc[2][8] = {};
  #pragma unroll
  for (int ks = 0; ks < 2; ks++) {
    const int k0 = ks * 32 + fg * 8;
    short8 qf[2], kf[8];
    #pragma unroll
    for (int mi = 0; mi < 2; mi++) qf[mi] = *(const short8*)&qp[(w*32 + mi*16 + fr) * HD + k0];
    #pragma unroll
    for (int ni = 0; ni < 8; ni++) kf[ni] = *(const short8*)&kp[(ni*16 + fr) * HD + k0];
    #pragma unroll
    for (int mi = 0; mi < 2; mi++)
      #pragma unroll
      for (int ni = 0; ni < 8; ni++)
        sacc[mi][ni] = __builtin_amdgcn_mfma_f32_16x16x32_bf16(qf[mi], kf[ni], sacc[mi][ni], 0, 0, 0);
  }
  // softmax (f32) + store P bf16
  const float* bt = biasT + (size_t)bh * SEQ * SEQ;
  #pragma unroll
  for (int mi = 0; mi < 2; mi++) {
    #pragma unroll
    for (int j = 0; j < 4; j++) {
      const int l = w*32 + mi*16 + fg*4 + j;
      float vals[8];
      float mx = -1e30f;
      #pragma unroll
      for (int ni = 0; ni < 8; ni++) {
        vals[ni] = sacc[mi][ni][j] * 0.125f + bt[l * SEQ + ni*16 + fr];
        mx = fmaxf(mx, vals[ni]);
      }
      #pragma unroll
      for (int d = 1; d < 16; d <<= 1) mx = fmaxf(mx, __shfl_xor(mx, d));
      float sum = 0.f;
      #pragma unroll
      for (int ni = 0; ni < 8; ni++) { vals[ni] = __expf(vals[ni] - mx); sum += vals[ni]; }
      #pragma unroll
      for (int d = 1; d < 16; d <<= 1) sum += __shfl_xor(sum, d);
      const float inv = 1.0f / sum;
      #pragma unroll
      for (int ni = 0; ni < 8; ni++) P[l * 136 + ni*16 + fr] = f2bf(vals[ni] * inv);
    }
  }
  __syncthreads();
  // O = P @ V  (vT rows are e, cols are s -> B^T-style frags)
  f32x4 oacc[2][4] = {};
  #pragma unroll
  for (int ss = 0; ss < 4; ss++) {
    const int s0 = ss * 32 + fg * 8;
    short8 pf[2], vf[4];
    #pragma unroll
    for (int mi = 0; mi < 2; mi++) pf[mi] = *(const short8*)&P[(w*32 + mi*16 + fr) * 136 + s0];
    #pragma unroll
    for (int ei = 0; ei < 4; ei++) vf[ei] = *(const short8*)&vT[(ei*16 + fr) * 136 + s0];
    #pragma unroll
    for (int mi = 0; mi < 2; mi++)
      #pragma unroll
      for (int ei = 0; ei < 4; ei++)
        oacc[mi][ei] = __builtin_amdgcn_mfma_f32_16x16x32_bf16(pf[mi], vf[ei], oacc[mi][ei], 0, 0, 0);
  }
  #pragma unroll
  for (int mi = 0; mi < 2; mi++)
    #pragma unroll
    for (int ei = 0; ei < 4; ei++)
      #pragma unroll
      for (int j = 0; j < 4; j++) {
        const int r = b * SEQ + w*32 + mi*16 + fg*4 + j;
        const int c = h * HD + ei*16 + fr;
        ab[(size_t)r * DM + c] = f2bf(oacc[mi][ei][j]);
      }
}

// ---------------- BatchNorm over (batch,seq) per channel ---------------------
__global__ __launch_bounds__(256)
void bn_partial(const float* __restrict__ x, float* __restrict__ p1, float* __restrict__ p2)
{
  const int t = threadIdx.x;
  const float* xp = x + (size_t)blockIdx.x * 32 * DM;
  float s0 = 0, s1 = 0, s2 = 0, q0 = 0, q1 = 0, q2 = 0;
  for (int r = 0; r < 32; r++) {
    const float a = xp[r * DM + t];
    const float b = xp[r * DM + t + 256];
    const float c = xp[r * DM + t + 512];
    s0 += a; q0 += a * a;
    s1 += b; q1 += b * b;
    s2 += c; q2 += c * c;
  }
  const int base = blockIdx.x * DM;
  p1[base + t] = s0;       p2[base + t] = q0;
  p1[base + t + 256] = s1; p2[base + t + 256] = q1;
  p1[base + t + 512] = s2; p2[base + t + 512] = q2;
}

__global__ __launch_bounds__(256)
void bn_final(const float* __restrict__ p1, const float* __restrict__ p2,
              const float* __restrict__ gamma, const float* __restrict__ beta,
              float* __restrict__ sc, float* __restrict__ sh)
{
  const int c = blockIdx.x * 256 + threadIdx.x;
  float s = 0, q = 0;
  for (int i = 0; i < BNBLK; i++) { s += p1[i * DM + c]; q += p2[i * DM + c]; }
  const float mean = s * (1.0f / MTOK);
  const float var = q * (1.0f / MTOK) - mean * mean;
  const float rstd = rsqrtf(var + 1e-5f);
  const float g = gamma[c] * rstd;
  sc[c] = g;
  sh[c] = beta[c] - mean * g;
}

__global__ __launch_bounds__(256)
void bn_apply(const float* __restrict__ xi, const float* __restrict__ sc,
              const float* __restrict__ sh, float* __restrict__ xo, u16* __restrict__ xb)
{
  const int i = blockIdx.x * 256 + threadIdx.x;   // float4 units, total 2752512
  const int cv = i % (DM / 4);
  float4 v = ((const float4*)xi)[i];
  const float4 s = ((const float4*)sc)[cv];
  const float4 h = ((const float4*)sh)[cv];
  float4 y;
  y.x = v.x * s.x + h.x; y.y = v.y * s.y + h.y;
  y.z = v.z * s.z + h.z; y.w = v.w * s.w + h.w;
  ((float4*)xo)[i] = y;
  if (xb) {
    us4 pk; pk[0] = f2bf(y.x); pk[1] = f2bf(y.y); pk[2] = f2bf(y.z); pk[3] = f2bf(y.w);
    *(us4*)(xb + (size_t)i * 4) = pk;
  }
}

// ---------------- setup kernels ----------------------------------------------
__global__ __launch_bounds__(256)
void init_x(const float* __restrict__ xi, float* __restrict__ xo, u16* __restrict__ xb)
{
  const int i = blockIdx.x * 256 + threadIdx.x;
  float4 v = ((const float4*)xi)[i];
  ((float4*)xo)[i] = v;
  us4 pk; pk[0] = f2bf(v.x); pk[1] = f2bf(v.y); pk[2] = f2bf(v.z); pk[3] = f2bf(v.w);
  *(us4*)(xb + (size_t)i * 4) = pk;
}

__global__ __launch_bounds__(256)
void conv_bf16(const float* __restrict__ s, u16* __restrict__ d, int n4)
{
  const int i = blockIdx.x * 256 + threadIdx.x;
  if (i >= n4) return;
  float4 v = ((const float4*)s)[i];
  us4 pk; pk[0] = f2bf(v.x); pk[1] = f2bf(v.y); pk[2] = f2bf(v.z); pk[3] = f2bf(v.w);
  *(us4*)(d + (size_t)i * 4) = pk;
}

__global__ __launch_bounds__(256)
void conv_qkvw(const float* __restrict__ wq, const float* __restrict__ wk,
               const float* __restrict__ wv, u16* __restrict__ d)
{
  const int i = blockIdx.x * 256 + threadIdx.x;   // float4 units, total 1327104
  const int per = QKVN * DM / 4;                  // 442368
  const int l = i / per;
  const int rem = i - l * per;
  const int r = rem / (DM / 4);
  const int cv = rem - r * (DM / 4);
  const float* srcrow;
  if (r < DM)          srcrow = wq + ((size_t)l * DM + r) * DM;
  else if (r < 2 * DM) srcrow = wk + ((size_t)l * DM + (r - DM)) * DM;
  else                 srcrow = wv + ((size_t)l * DM + (r - 2 * DM)) * DM;
  float4 v = ((const float4*)srcrow)[cv];
  us4 pk; pk[0] = f2bf(v.x); pk[1] = f2bf(v.y); pk[2] = f2bf(v.z); pk[3] = f2bf(v.w);
  *(us4*)(d + (size_t)i * 4) = pk;
}

__global__ __launch_bounds__(256)
void conv_bias_qkv(const float* __restrict__ bq, const float* __restrict__ bk,
                   const float* __restrict__ bv, float* __restrict__ d)
{
  const int i = blockIdx.x * 256 + threadIdx.x;   // 6912
  const int l = i / QKVN;
  const int r = i - l * QKVN;
  float v;
  if (r < DM)          v = bq[l * DM + r];
  else if (r < 2 * DM) v = bk[l * DM + r - DM];
  else                 v = bv[l * DM + r - 2 * DM];
  d[i] = v;
}

__global__ __launch_bounds__(256)
void bias_tr(const float* __restrict__ src, float* __restrict__ dst)
{
  const int l = blockIdx.x, b = blockIdx.y;
  __shared__ float row[SEQ * NH];   // 1536
  const float* s = src + ((size_t)b * SEQ + l) * SEQ * NH;
  for (int i = threadIdx.x; i < SEQ * NH; i += 256) row[i] = s[i];
  __syncthreads();
  for (int i = threadIdx.x; i < SEQ * NH; i += 256) {
    const int h = i >> 7, ss = i & 127;
    dst[((size_t)(b * NH + h) * SEQ + l) * SEQ + ss] = row[ss * NH + h];
  }
}

// ---------------- launch -----------------------------------------------------
extern "C" void kernel_launch(void* const* d_in, const int* in_sizes, int n_in,
                              void* d_out, int out_size, void* d_ws, size_t ws_size,
                              hipStream_t stream)
{
  const float* x    = (const float*)d_in[0];
  const float* abia = (const float*)d_in[1];
  const float* Wq   = (const float*)d_in[2];
  const float* bq   = (const float*)d_in[3];
  const float* Wk   = (const float*)d_in[4];
  const float* bk   = (const float*)d_in[5];
  const float* Wv   = (const float*)d_in[6];
  const float* bv   = (const float*)d_in[7];
  const float* Wo   = (const float*)d_in[8];
  const float* bo   = (const float*)d_in[9];
  const float* W1   = (const float*)d_in[10];
  const float* b1   = (const float*)d_in[11];
  const float* W2   = (const float*)d_in[12];
  const float* b2   = (const float*)d_in[13];
  const float* g1   = (const float*)d_in[14];
  const float* be1  = (const float*)d_in[15];
  const float* g2   = (const float*)d_in[16];
  const float* be2  = (const float*)d_in[17];
  const float* gf   = (const float*)d_in[18];
  const float* bef  = (const float*)d_in[19];
  float* out = (float*)d_out;

  char* ws = (char*)d_ws;
  size_t off = 0;
  auto alloc = [&](size_t n) -> char* {
    char* p = ws + off;
    off = (off + n + 255) & ~(size_t)255;
    return p;
  };
  u16*  wqkv  = (u16*)alloc((size_t)3 * QKVN * DM * 2);
  u16*  wo    = (u16*)alloc((size_t)3 * DM * DM * 2);
  u16*  w1    = (u16*)alloc((size_t)3 * FF * DM * 2);
  u16*  w2    = (u16*)alloc((size_t)3 * DM * FF * 2);
  float* bqkv = (float*)alloc((size_t)3 * QKVN * 4);
  u16*  xb    = (u16*)alloc((size_t)MTOK * DM * 2);
  u16*  ab    = (u16*)alloc((size_t)MTOK * DM * 2);
  u16*  big   = (u16*)alloc((size_t)MTOK * FF * 2);       // qkv (66MB) / ffn-mid (88MB) shared
  float* biasT = (float*)alloc((size_t)HEADTOT * SEQ * SEQ * 4);
  float* p1   = (float*)alloc((size_t)BNBLK * DM * 4);
  float* p2   = (float*)alloc((size_t)BNBLK * DM * 4);
  float* sc   = (float*)alloc(DM * 4);
  float* sh   = (float*)alloc(DM * 4);
  if (off > ws_size) return;   // workspace too small: fail visibly without OOB writes

  conv_qkvw<<<5184, 256, 0, stream>>>(Wq, Wk, Wv, wqkv);
  conv_bf16<<<1728, 256, 0, stream>>>(Wo, wo, 3 * DM * DM / 4);
  conv_bf16<<<6912, 256, 0, stream>>>(W1, w1, 3 * FF * DM / 4);
  conv_bf16<<<6912, 256, 0, stream>>>(W2, w2, 3 * DM * FF / 4);
  conv_bias_qkv<<<27, 256, 0, stream>>>(bq, bk, bv, bqkv);
  bias_tr<<<dim3(SEQ, NB), 256, 0, stream>>>(abia, biasT);
  init_x<<<MTOK * DM / 4 / 256, 256, 0, stream>>>(x, out, xb);

  for (int l = 0; l < NLAYER; l++) {
    gemm_bt<3><<<dim3(QKVN / BN, MTOK / BM), 256, 0, stream>>>(
        xb, wqkv + (size_t)l * QKVN * DM, bqkv + l * QKVN, big, nullptr, nullptr,
        MTOK, QKVN, DM);
    attn_kernel<<<dim3(NH, NB), 256, 0, stream>>>(big, biasT, ab);
    gemm_bt<2><<<dim3(DM / BN, MTOK / BM), 256, 0, stream>>>(
        ab, wo + (size_t)l * DM * DM, bo + l * DM, nullptr, out, out,
        MTOK, DM, DM);
    bn_partial<<<BNBLK, 256, 0, stream>>>(out, p1, p2);
    bn_final<<<3, 256, 0, stream>>>(p1, p2, g1 + l * DM, be1 + l * DM, sc, sh);
    bn_apply<<<MTOK * DM / 4 / 256, 256, 0, stream>>>(out, sc, sh, out, xb);
    gemm_bt<1><<<dim3(FF / BN, MTOK / BM), 256, 0, stream>>>(
        xb, w1 + (size_t)l * FF * DM, b1 + l * FF, big, nullptr, nullptr,
        MTOK, FF, DM);
    gemm_bt<2><<<dim3(DM / BN, MTOK / BM), 256, 0, stream>>>(
        big, w2 + (size_t)l * DM * FF, b2 + l * DM, nullptr, out, out,
        MTOK, DM, FF);
    bn_partial<<<BNBLK, 256, 0, stream>>>(out, p1, p2);
    bn_final<<<3, 256, 0, stream>>>(p1, p2, g2 + l * DM, be2 + l * DM, sc, sh);
    bn_apply<<<MTOK * DM / 4 / 256, 256, 0, stream>>>(out, sc, sh, out, xb);
  }
  bn_partial<<<BNBLK, 256, 0, stream>>>(out, p1, p2);
  bn_final<<<3, 256, 0, stream>>>(p1, p2, gf, bef, sc, sh);
  bn_apply<<<MTOK * DM / 4 / 256, 256, 0, stream>>>(out, sc, sh, out, nullptr);
}